// Round 11
// baseline (97.567 us; speedup 1.0000x reference)
//
#include <hip/hip_runtime.h>

typedef _Float16 f16x4 __attribute__((ext_vector_type(4)));
typedef _Float16 f16x8 __attribute__((ext_vector_type(8)));
typedef unsigned short u16x8 __attribute__((ext_vector_type(8)));
typedef float f32x4 __attribute__((ext_vector_type(4)));

#define NS 1024
#define NQ 1024
#define DD 128
#define NWAY 8
#define SCHUNK 64            // supports per block (4 waves x 16)
#define NSBLK (NS / SCHUNK)  // 16
#define QPER 32              // queries per block -> grid 512 = 2 blocks/CU

// d_ws layout (bytes):
//   0x000000  simM  [NQ][NS] f32            (4 MB)
//   0x400000  sup16 [NS][DD] f16            (256 KB)
//   0x440000  q16   [NQ][DD] f16            (256 KB)
//   0x480000  w1f   [16 frag][64 lane][8] f16 (16 KB, fragment-ordered)
//   0x484000  onehot[NS][8] f32             (32 KB)
//   0x48C000  counts[8] f32

// Prep: f32->f16 conversion of support/query/W1 (W1 in MFMA fragment
// order) + one-hot label matrix + class counts. Keeping conversions out
// of main removes the cvt/float4 peak register pressure (spills R3/R5/R7).
__global__ void siamese_prep(const float* __restrict__ sx,
                             const float* __restrict__ qx,
                             const float* __restrict__ W1,
                             const int* __restrict__ sy,
                             _Float16* __restrict__ sup16,
                             _Float16* __restrict__ q16,
                             _Float16* __restrict__ w1f,
                             float* __restrict__ onehot,
                             float* __restrict__ counts)
{
    const int tid = blockIdx.x * 256 + threadIdx.x;
    if (blockIdx.x < 128) {                       // support: 32768 float4
        float4 v = ((const float4*)sx)[tid];
        f16x4 h; h[0] = (_Float16)v.x; h[1] = (_Float16)v.y;
        h[2] = (_Float16)v.z; h[3] = (_Float16)v.w;
        ((f16x4*)sup16)[tid] = h;
    } else if (blockIdx.x < 256) {                // query: 32768 float4
        const int i = tid - 32768;
        float4 v = ((const float4*)qx)[i];
        f16x4 h; h[0] = (_Float16)v.x; h[1] = (_Float16)v.y;
        h[2] = (_Float16)v.z; h[3] = (_Float16)v.w;
        ((f16x4*)q16)[i] = h;
    } else if (blockIdx.x < 260) {                // W1 frags: 16*64 = 1024
        const int i = tid - 65536;
        const int jk = i >> 6, l = i & 63;
        const int h = (jk >> 2) * 16 + (l & 15);
        const int d = (jk & 3) * 32 + (l >> 4) * 8;
        const float* wp = W1 + h * DD + d;
        float4 v0 = *(const float4*)(wp);
        float4 v1 = *(const float4*)(wp + 4);
        f16x8 s;
        s[0] = (_Float16)v0.x; s[1] = (_Float16)v0.y;
        s[2] = (_Float16)v0.z; s[3] = (_Float16)v0.w;
        s[4] = (_Float16)v1.x; s[5] = (_Float16)v1.y;
        s[6] = (_Float16)v1.z; s[7] = (_Float16)v1.w;
        *(f16x8*)(w1f + (size_t)i * 8) = s;
    } else if (blockIdx.x < 268) {                // one-hot: 2048 float4
        const int i = tid - 66560;
        const int s = i >> 1, half = i & 1;
        const int lab = sy[s];
        float4 v;
        v.x = (lab == half * 4 + 0) ? 1.f : 0.f;
        v.y = (lab == half * 4 + 1) ? 1.f : 0.f;
        v.z = (lab == half * 4 + 2) ? 1.f : 0.f;
        v.w = (lab == half * 4 + 3) ? 1.f : 0.f;
        ((float4*)onehot)[i] = v;
    } else {                                      // counts
        __shared__ float cnt[NWAY];
        const int t = threadIdx.x;
        if (t < NWAY) cnt[t] = 0.f;
        __syncthreads();
#pragma unroll
        for (int i = 0; i < 4; ++i)
            atomicAdd(&cnt[sy[t * 4 + i]], 1.0f);
        __syncthreads();
        if (t < NWAY) counts[t] = cnt[t];
    }
}

// Main: 64 supports x 32 queries per block, grid 512 = exactly 2 blocks/CU
// at (256,2) -> one co-resident round.
// sim(q,s) = relu(|q-s| @ W1^T + b1) @ W2; b2 dropped (log_softmax
// shift-invariant). MFMA: A = W1 frag, B = diff frag -> C rows h, cols s.
// R11 change: NO LDS atomics — sim values go straight to a global SIM
// matrix with plain fire-and-forget 64B stores. R10's LDS ds_atomic_add
// (16 lanes onto 8 addresses, every q) serialized on the LDS pipe and was
// the dominant un-hideable stall (~2-5k cyc/wave).
// launch_bounds MUST stay (256,2): tighter caps (R3/R5/R7) all spilled.
__global__ __launch_bounds__(256, 2) void siamese_main(
    const _Float16* __restrict__ sup16,
    const _Float16* __restrict__ q16,
    const _Float16* __restrict__ w1f,
    const float* __restrict__ b1,
    const float* __restrict__ W2,
    float* __restrict__ simM)   // [NQ][NS]
{
    __shared__ _Float16 qtile[QPER][DD];       // 8 KB

    const int t = threadIdx.x;
    const int wave = t >> 6;
    const int lane = t & 63;
    const int c = lane & 15;     // MFMA n index -> support col
    const int quad = lane >> 4;  // MFMA k-group / C row-group

    const int sblk = blockIdx.x & (NSBLK - 1);
    const int qblk = blockIdx.x >> 4;
    const int s0 = sblk * SCHUNK;
    const int q0 = qblk * QPER;

    // ---- one-time: support B-fragments (pure f16 16B loads) ----
    f16x8 sup[4];
    {
        const _Float16* sp = sup16 + (size_t)(s0 + wave * 16 + c) * DD + quad * 8;
#pragma unroll
        for (int k = 0; k < 4; ++k)
            sup[k] = *(const f16x8*)(sp + k * 32);
    }

    // ---- one-time: W1 A-fragments (fragment-ordered, 16B loads) ----
    f16x8 afrag[4][4];
#pragma unroll
    for (int j = 0; j < 4; ++j)
#pragma unroll
        for (int k = 0; k < 4; ++k)
            afrag[j][k] = *(const f16x8*)(w1f + (size_t)((j * 4 + k) * 64 + lane) * 8);

    // ---- one-time: b1/W2 rows for this lane (h = j*16 + quad*4 + r) ----
    f32x4 b1v[4], w2v[4];
#pragma unroll
    for (int j = 0; j < 4; ++j) {
        b1v[j] = *(const f32x4*)(b1 + j * 16 + quad * 4);
        w2v[j] = *(const f32x4*)(W2 + j * 16 + quad * 4);
    }

    // ---- stage QPER query rows (f16, 16B copies; 2 chunks/thread) ----
#pragma unroll
    for (int i = 0; i < 2; ++i) {
        const int idx = t + i * 256;
        const int q = idx >> 4;
        const int dd = (idx & 15) * 8;
        *(f16x8*)&qtile[q][dd] = *(const f16x8*)(q16 + (size_t)(q0 + q) * DD + dd);
    }
    __syncthreads();

    // sim store base for this wave's 16 support columns
    float* simBase = simM + (size_t)q0 * NS + s0 + wave * 16 + c;

    auto read_qf = [&](f16x8 (&qf)[4], int qq) {
#pragma unroll
        for (int k = 0; k < 4; ++k)
            qf[k] = *(const f16x8*)&qtile[qq][k * 32 + quad * 8];
    };
    auto mfma_q = [&](f32x4 (&acc)[4], const f16x8 (&qf)[4]) {
#pragma unroll
        for (int j = 0; j < 4; ++j) acc[j] = b1v[j];
#pragma unroll
        for (int k = 0; k < 4; ++k) {
            union { f16x8 f; u16x8 u; } cv;
            cv.f = sup[k] - qf[k];
            cv.u = cv.u & (unsigned short)0x7fffu;  // |diff|
#pragma unroll
            for (int j = 0; j < 4; ++j)
                acc[j] = __builtin_amdgcn_mfma_f32_16x16x32_f16(
                    afrag[j][k], cv.f, acc[j], 0, 0, 0);
        }
    };
    auto epi = [&](const f32x4 (&acc)[4], int qq) {
        float val = 0.f;
#pragma unroll
        for (int j = 0; j < 4; ++j)
#pragma unroll
            for (int r = 0; r < 4; ++r)
                val = fmaf(fmaxf(acc[j][r], 0.f), w2v[j][r], val);
        val += __shfl_xor(val, 16);
        val += __shfl_xor(val, 32);
        if (quad == 0)
            simBase[(size_t)qq * NS] = val;   // fire-and-forget 64B store
    };

    // -------- modulo-2 skewed pipeline over the 32 queries --------
    f16x8 qfA[4], qfB[4];
    f32x4 accA[4], accB[4];
    read_qf(qfA, 0);
    mfma_q(accA, qfA);
    read_qf(qfB, 1);
    for (int qq = 0; qq + 2 < QPER; qq += 2) {
        mfma_q(accB, qfB);      // MFMAs for qq+1 ...
        epi(accA, qq);          // ... interleave with epilogue of qq
        read_qf(qfA, qq + 2);
        mfma_q(accA, qfA);      // MFMAs for qq+2 ...
        epi(accB, qq + 1);      // ... interleave with epilogue of qq+1
        read_qf(qfB, qq + 3);
    }
    mfma_q(accB, qfB);
    epi(accA, QPER - 2);
    epi(accB, QPER - 1);
}

// Finalize: class sums = SIM row x one-hot, mean, log_softmax.
// Grid 256 x 256: 4 queries per block, 64 lanes per query, no atomics.
__global__ void siamese_finalize(
    const float* __restrict__ simM,
    const float* __restrict__ onehot,
    const float* __restrict__ counts,
    float* __restrict__ out)
{
    const int t = threadIdx.x;
    const int q = blockIdx.x * 4 + (t >> 6);
    const int lane = t & 63;

    f32x4 slo = (f32x4){0.f, 0.f, 0.f, 0.f};
    f32x4 shi = (f32x4){0.f, 0.f, 0.f, 0.f};
    const float* srow = simM + (size_t)q * NS + lane * 16;
    const f32x4* oh = (const f32x4*)(onehot) + (size_t)lane * 32;  // 16 s x 2
#pragma unroll
    for (int i = 0; i < 4; ++i) {
        f32x4 sv = *(const f32x4*)(srow + i * 4);
#pragma unroll
        for (int e = 0; e < 4; ++e) {
            const float v = sv[e];
            slo += v * oh[(i * 4 + e) * 2];
            shi += v * oh[(i * 4 + e) * 2 + 1];
        }
    }
    // reduce across the 64 lanes of this query
#pragma unroll
    for (int off = 1; off < 64; off <<= 1) {
#pragma unroll
        for (int e = 0; e < 4; ++e) {
            slo[e] += __shfl_xor(slo[e], off);
            shi[e] += __shfl_xor(shi[e], off);
        }
    }
    if (lane == 0) {
        const f32x4 clo = *(const f32x4*)(counts);
        const f32x4 chi = *(const f32x4*)(counts + 4);
        f32x4 lo = slo / clo;
        f32x4 hi = shi / chi;
        float mx = fmaxf(fmaxf(fmaxf(lo[0], lo[1]), fmaxf(lo[2], lo[3])),
                         fmaxf(fmaxf(hi[0], hi[1]), fmaxf(hi[2], hi[3])));
        float ss = 0.f;
#pragma unroll
        for (int k = 0; k < 4; ++k) ss += expf(lo[k] - mx);
#pragma unroll
        for (int k = 0; k < 4; ++k) ss += expf(hi[k] - mx);
        const float lse = mx + logf(ss);
#pragma unroll
        for (int k = 0; k < 4; ++k) lo[k] -= lse;
#pragma unroll
        for (int k = 0; k < 4; ++k) hi[k] -= lse;
        *(f32x4*)(out + (size_t)q * NWAY) = lo;
        *(f32x4*)(out + (size_t)q * NWAY + 4) = hi;
    }
}

extern "C" void kernel_launch(void* const* d_in, const int* in_sizes, int n_in,
                              void* d_out, int out_size, void* d_ws, size_t ws_size,
                              hipStream_t stream) {
    const float* support_x = (const float*)d_in[0];
    const int* support_y   = (const int*)d_in[1];
    const float* query_x   = (const float*)d_in[2];
    // d_in[3] = n_way (scalar, fixed at 8) — unused
    const float* W1 = (const float*)d_in[4];
    const float* b1 = (const float*)d_in[5];
    const float* W2 = (const float*)d_in[6];
    // d_in[7] = b2 — dropped (uniform logit shift, log_softmax-invariant)

    char* ws = (char*)d_ws;
    float* simM       = (float*)(ws);                  // 4 MB
    _Float16* sup16   = (_Float16*)(ws + 0x400000);    // 256 KB
    _Float16* q16     = (_Float16*)(ws + 0x440000);    // 256 KB
    _Float16* w1f     = (_Float16*)(ws + 0x480000);    // 16 KB
    float* onehot     = (float*)(ws + 0x484000);       // 32 KB
    float* counts     = (float*)(ws + 0x48C000);       // 32 B

    siamese_prep<<<dim3(269), dim3(256), 0, stream>>>(
        support_x, query_x, W1, support_y, sup16, q16, w1f, onehot, counts);
    siamese_main<<<dim3(NSBLK * (NQ / QPER)), dim3(256), 0, stream>>>(
        sup16, q16, w1f, b1, W2, simM);
    siamese_finalize<<<dim3(NQ / 4), dim3(256), 0, stream>>>(
        simM, onehot, counts, (float*)d_out);
}